// Round 11
// baseline (6275.750 us; speedup 1.0000x reference)
//
#include <hip/hip_runtime.h>
#include <hip/hip_bf16.h>
#include <cstdint>
#include <cstring>

#define T_DIM 2048
#define B_DIM 64
#define H_DIM 256
#define NSLOT 4096
#define NWG_REC 128
#define HSTRIDE 264   // shorts; 528B rows, 16B-aligned

typedef __attribute__((ext_vector_type(8))) short bf16x8;
typedef __attribute__((ext_vector_type(4))) float f32x4;
typedef __attribute__((ext_vector_type(4))) short short4v;

// ---------------- ws layout (bytes) ----------------
static const size_t WS_GI      = 0;           // 201326592  gi bf16 T*B*768
static const size_t WS_RST     = 201326592;   // 131072     resets u8
static const size_t WS_FLAG    = 201457664;   // 8          dtype flag
static const size_t WS_DESC    = 201457672;   // 32768      per-slot segment desc u64[4096]
static const size_t WS_WGSTEPS = 201490440;   // 512        u32[128]
// end ~201.5 MB (< proven 213.5 MB)

// desc u64: b:0-7 | hinit:8 | start:16-27 | len:32-47 ; 0 = empty slot

static __device__ __forceinline__ short f2bs(float f) {
  __hip_bfloat16 b = __float2bfloat16(f);
  short s; memcpy(&s, &b, 2); return s;
}
static __device__ __forceinline__ float bs2f(unsigned short u) {
  uint32_t v = ((uint32_t)u) << 16; float f; memcpy(&f, &v, 4); return f;
}
static __device__ __forceinline__ float sigm(float x) {
  return 1.f / (1.f + __expf(-x));
}
static __device__ __forceinline__ float tanh_fast(float x) {
  return 1.f - 2.f / (__expf(2.f * x) + 1.f);
}

// ---------------- resets dtype detection (verified R1-R10) ----------------
__global__ __launch_bounds__(256) void detect_resets(const uint32_t* __restrict__ rbuf,
                                                     int* __restrict__ flag_out) {
  __shared__ int v_u8, v_f32;
  if (threadIdx.x == 0) { v_u8 = 0; v_f32 = 0; }
  __syncthreads();
  int cu = 0, cf = 0;
  for (int i = threadIdx.x; i < 32768; i += 256) {
    uint32_t w = rbuf[i];
    if (w == 0x3F800000u) cf++;
    else if (w > 1u && (w & 0xFEFEFEFEu) == 0u) cu++;
  }
  atomicAdd(&v_u8, cu);
  atomicAdd(&v_f32, cf);
  __syncthreads();
  if (threadIdx.x == 0) *flag_out = (v_f32 > 0) ? 2 : ((v_u8 > 0) ? 1 : 0);
}

__global__ __launch_bounds__(256) void expand_resets(const void* __restrict__ rbuf,
                                                     const int* __restrict__ flag,
                                                     uint8_t* __restrict__ out) {
  int i = blockIdx.x * 256 + threadIdx.x;
  if (i >= T_DIM * B_DIM) return;
  int f = *flag;
  uint8_t v;
  if (f == 1)      v = (((const uint8_t*)rbuf)[i] != 0);
  else if (f == 2) v = (((const float*)rbuf)[i] != 0.f);
  else             v = (((const int*)rbuf)[i] != 0);
  out[i] = v;
}

// ---------------- build segment schedule: per-slot descriptors ----------------
// Segment s (b-major order) -> wg = s%128, j = s/128 (<32), slot = wg*32 +
// (j&1)*16 + (j/2).  Group A = local slots 0-15, group B = 16-31; segments
// alternate groups so each WG's two pipelines are balanced.
__global__ __launch_bounds__(1024) void build_schedule(const uint8_t* __restrict__ rst,
                                                       uint64_t* __restrict__ desc,
                                                       uint32_t* __restrict__ wgsteps) {
  __shared__ uint32_t cnt[64];
  __shared__ uint32_t offs[65];
  const int tid = threadIdx.x;

  for (int i = tid; i < NSLOT; i += 1024) desc[i] = 0;
  __syncthreads();

  if (tid < 64) {
    int b = tid, k = 1;
    for (int t = 1; t < 2048; ++t) k += rst[t * 64 + b];
    cnt[b] = k;
  }
  __syncthreads();
  if (tid == 0) {
    uint32_t a = 0;
    for (int b2 = 0; b2 < 64; ++b2) { offs[b2] = a; a += cnt[b2]; }
    offs[64] = a;
  }
  __syncthreads();
  if (tid < 64) {
    int b = tid;
    uint32_t o = offs[b];
    int h0flag = rst[b] ? 0 : 1;
    int prev = 0;
    for (int t = 1; t < 2048; ++t) {
      if (rst[t * 64 + b]) {
        uint32_t hin = (prev == 0) ? (uint32_t)h0flag : 0u;
        if (o < NSLOT) {
          uint32_t slot = (o & 127u) * 32 + ((o >> 7) & 1u) * 16 + (o >> 8);
          desc[slot] = ((uint64_t)(uint32_t)(t - prev) << 32) |
                       ((uint32_t)prev << 16) | (hin << 8) | (uint32_t)b;
        }
        o++;
        prev = t;
      }
    }
    uint32_t hin = (prev == 0) ? (uint32_t)h0flag : 0u;
    if (o < NSLOT) {
      uint32_t slot = (o & 127u) * 32 + ((o >> 7) & 1u) * 16 + (o >> 8);
      desc[slot] = ((uint64_t)(uint32_t)(2048 - prev) << 32) |
                   ((uint32_t)prev << 16) | (hin << 8) | (uint32_t)b;
    }
  }
  __syncthreads();

  if (tid < NWG_REC) {
    uint32_t mx = 0;
#pragma unroll
    for (int q = 0; q < 32; ++q) {
      uint32_t len = (uint32_t)(desc[tid * 32 + q] >> 32) & 0xFFFFu;
      mx = mx > len ? mx : len;
    }
    wgsteps[tid] = mx;
  }
}

// ---------------- gi = x @ Wi + bi via MFMA (verified R2-R10) ----------------
__global__ __launch_bounds__(1024) void gi_gemm_mfma(const float* __restrict__ x,
                                                     const float* __restrict__ Wi,
                                                     const float* __restrict__ bi,
                                                     unsigned short* __restrict__ gi16) {
  __shared__ short hfrag[32 * 136];
  const int tid = threadIdx.x;
  const int lane = tid & 63, wave = tid >> 6;
  const int lq = lane >> 4, l15 = lane & 15;

  bf16x8 wfrag[3][8];
  const int colb = wave * 48 + l15;
#pragma unroll
  for (int nt = 0; nt < 3; ++nt) {
#pragma unroll
    for (int ks = 0; ks < 8; ++ks) {
      bf16x8 f;
#pragma unroll
      for (int e = 0; e < 8; ++e)
        f[e] = f2bs(Wi[(size_t)(ks * 32 + lq * 8 + e) * 768 + colb + nt * 16]);
      wfrag[nt][ks] = f;
    }
  }
  const float b0 = bi[colb], b1 = bi[colb + 16], b2 = bi[colb + 32];

  const int r = wave;
  const int kc = (tid & 63) * 4;
  const size_t m0 = (size_t)blockIdx.x * 32 * 16;

  float4 xv = *(const float4*)&x[(m0 + r) * 256 + kc];
  for (int i = 0; i < 32; ++i) {
    short4v xb = { f2bs(xv.x), f2bs(xv.y), f2bs(xv.z), f2bs(xv.w) };
    *(short4v*)&hfrag[(kc >> 3) * 136 + r * 8 + (kc & 7)] = xb;
    __syncthreads();
    if (i + 1 < 32)
      xv = *(const float4*)&x[(m0 + (size_t)(i + 1) * 16 + r) * 256 + kc];
    f32x4 c0 = {0.f,0.f,0.f,0.f}, c1 = {0.f,0.f,0.f,0.f}, c2 = {0.f,0.f,0.f,0.f};
#pragma unroll
    for (int ks = 0; ks < 8; ++ks) {
      bf16x8 a = *(const bf16x8*)&hfrag[(ks * 4 + lq) * 136 + l15 * 8];
      c0 = __builtin_amdgcn_mfma_f32_16x16x32_bf16(a, wfrag[0][ks], c0, 0, 0, 0);
      c1 = __builtin_amdgcn_mfma_f32_16x16x32_bf16(a, wfrag[1][ks], c1, 0, 0, 0);
      c2 = __builtin_amdgcn_mfma_f32_16x16x32_bf16(a, wfrag[2][ks], c2, 0, 0, 0);
    }
    __syncthreads();
    const size_t rowb = m0 + (size_t)i * 16;
#pragma unroll
    for (int qq = 0; qq < 4; ++qq) {
      const size_t row = rowb + lq * 4 + qq;
      gi16[row * 768 + colb]      = (unsigned short)f2bs(c0[qq] + b0);
      gi16[row * 768 + colb + 16] = (unsigned short)f2bs(c1[qq] + b1);
      gi16[row * 768 + colb + 32] = (unsigned short)f2bs(c2[qq] + b2);
    }
  }
}

#define LOADG(G, p) do {                        \
    (G)[0][0] = *(const ushort4*)&(p)[0];       \
    (G)[0][1] = *(const ushort4*)&(p)[256];     \
    (G)[0][2] = *(const ushort4*)&(p)[512];     \
    (G)[1][0] = *(const ushort4*)&(p)[16];      \
    (G)[1][1] = *(const ushort4*)&(p)[272];     \
    (G)[1][2] = *(const ushort4*)&(p)[528];     \
  } while (0)

// ---------------- segment-parallel GRU recurrence, 2-group pipeline ----------------
// 128 WGs x 8 waves (R8 resource envelope: Wr/Wz 2 tiles = 128 AGPR, Wn in LDS).
// WG owns 32 slots: group A (local 0-15) and group B (16-31), two independent
// recurrence sets software-pipelined: each phase runs one group's MFMA (matrix
// pipe + LDS) overlapped with the other group's pointwise (VALU/TRANS) and
// h-writeback. hfA/hfB single-buffered: reads drain at the barrier before the
// opposite phase overwrites. gi loads issue a full phase ahead.
__global__ __launch_bounds__(512, 1) void gru_rec_seg(const unsigned short* __restrict__ gi16,
                                                      const float* __restrict__ h0,
                                                      const float* __restrict__ Whr,
                                                      const float* __restrict__ Whz,
                                                      const float* __restrict__ Whn,
                                                      const float* __restrict__ bhn,
                                                      const uint64_t* __restrict__ desc,
                                                      const uint32_t* __restrict__ wgsteps,
                                                      float* __restrict__ out) {
  __shared__ short wn_lds[256 * HSTRIDE];     // Wn^T: [col][k], 135KB
  __shared__ short hfA[16 * HSTRIDE];         // group A h^T, 8.4KB
  __shared__ short hfB[16 * HSTRIDE];         // group B h^T, 8.4KB
  const int tid = threadIdx.x;
  const int lane = tid & 63, w = tid >> 6;    // w in [0,8)
  const int lq = lane >> 4, l15 = lane & 15;
  const int wg = blockIdx.x;

  // resident Wr/Wz A-fragments for both tiles (128 regs, AGPR — R8-proven)
  bf16x8 wfragR[2][8], wfragZ[2][8];
#pragma unroll
  for (int nt = 0; nt < 2; ++nt) {
    const int wcol = w * 32 + nt * 16 + l15;
#pragma unroll
    for (int ks = 0; ks < 8; ++ks) {
      bf16x8 fr, fz;
#pragma unroll
      for (int e = 0; e < 8; ++e) {
        fr[e] = f2bs(Whr[(size_t)(ks * 32 + lq * 8 + e) * 256 + wcol]);
        fz[e] = f2bs(Whz[(size_t)(ks * 32 + lq * 8 + e) * 256 + wcol]);
      }
      wfragR[nt][ks] = fr; wfragZ[nt][ks] = fz;
    }
  }

  // stage Wn^T into LDS col-major
  {
    const int col = tid & 255, kb = (tid >> 8) * 128;
    for (int kk = 0; kk < 128; kk += 4) {
      short4v v;
#pragma unroll
      for (int u = 0; u < 4; ++u)
        v[u] = f2bs(Whn[(size_t)(kb + kk + u) * 256 + col]);
      *(short4v*)&wn_lds[col * HSTRIDE + kb + kk] = v;
    }
  }

  const int col0 = w * 32 + lq * 4;           // tile0 cols; tile1 = +16
  const float4 bn0 = *(const float4*)&bhn[col0];
  const float4 bn1 = *(const float4*)&bhn[col0 + 16];
  const int nsteps = (int)wgsteps[wg];

  // group descriptors (slot of l15: A = wg*32+l15, B = wg*32+16+l15)
  const uint64_t dA = desc[(size_t)wg * 32 + l15];
  const uint64_t dB = desc[(size_t)wg * 32 + 16 + l15];
  const uint32_t bA = (uint32_t)dA & 63u, bB = (uint32_t)dB & 63u;
  const int lenA = (int)((uint32_t)(dA >> 32) & 0xFFFFu);
  const int lenB = (int)((uint32_t)(dB >> 32) & 0xFFFFu);
  const int startA = (int)(((uint32_t)dA >> 16) & 0xFFFu);
  const int startB = (int)(((uint32_t)dB >> 16) & 0xFFFu);
  const bool lastA = (startA + lenA == 2048);
  const bool lastB = (startB + lenB == 2048);

  const unsigned short* gptrA = gi16 + ((size_t)(startA * 64 + (int)bA)) * 768 + col0;
  const unsigned short* gptrB = gi16 + ((size_t)(startB * 64 + (int)bB)) * 768 + col0;
  float* optrA = out + 16384 + ((size_t)(startA * 64 + (int)bA)) * 256 + col0;
  float* optrB = out + 16384 + ((size_t)(startB * 64 + (int)bB)) * 256 + col0;

  // init h (packed bf16 per tile) + hfrag writes
  short4v hpA[2], hpB[2];
  {
    float4 v0 = {0.f,0.f,0.f,0.f}, v1 = {0.f,0.f,0.f,0.f};
    if (lenA > 0 && (((uint32_t)dA >> 8) & 1u)) {
      v0 = *(const float4*)&h0[(size_t)bA * 256 + col0];
      v1 = *(const float4*)&h0[(size_t)bA * 256 + col0 + 16];
    }
    hpA[0] = (short4v){ f2bs(v0.x), f2bs(v0.y), f2bs(v0.z), f2bs(v0.w) };
    hpA[1] = (short4v){ f2bs(v1.x), f2bs(v1.y), f2bs(v1.z), f2bs(v1.w) };
    *(short4v*)&hfA[l15 * HSTRIDE + col0] = hpA[0];
    *(short4v*)&hfA[l15 * HSTRIDE + col0 + 16] = hpA[1];
    v0 = (float4){0.f,0.f,0.f,0.f}; v1 = (float4){0.f,0.f,0.f,0.f};
    if (lenB > 0 && (((uint32_t)dB >> 8) & 1u)) {
      v0 = *(const float4*)&h0[(size_t)bB * 256 + col0];
      v1 = *(const float4*)&h0[(size_t)bB * 256 + col0 + 16];
    }
    hpB[0] = (short4v){ f2bs(v0.x), f2bs(v0.y), f2bs(v0.z), f2bs(v0.w) };
    hpB[1] = (short4v){ f2bs(v1.x), f2bs(v1.y), f2bs(v1.z), f2bs(v1.w) };
    *(short4v*)&hfB[l15 * HSTRIDE + col0] = hpB[0];
    *(short4v*)&hfB[l15 * HSTRIDE + col0 + 16] = hpB[1];
  }

  // prologue gi loads (step 0 of both groups)
  ushort4 GA[2][3], GB[2][3];
  LOADG(GA, gptrA); if (lenA > 1) gptrA += 64 * 768;
  LOADG(GB, gptrB); if (lenB > 1) gptrB += 64 * 768;
  __syncthreads();

  const short* wnb0 = &wn_lds[(w * 32 + l15) * HSTRIDE + lq * 8];
  const short* wnb1 = &wn_lds[(w * 32 + 16 + l15) * HSTRIDE + lq * 8];
  const short* hbA = &hfA[l15 * HSTRIDE + lq * 8];
  const short* hbB = &hfB[l15 * HSTRIDE + lq * 8];

  f32x4 cA0[2], cA1[2], cA2[2], cB0[2], cB1[2], cB2[2];

#define MFMA_GROUP(c0_, c1_, c2_, hb_)                                              \
  do {                                                                              \
    c0_[0] = (f32x4){0.f,0.f,0.f,0.f}; c0_[1] = (f32x4){0.f,0.f,0.f,0.f};           \
    c1_[0] = (f32x4){0.f,0.f,0.f,0.f}; c1_[1] = (f32x4){0.f,0.f,0.f,0.f};           \
    c2_[0] = (f32x4){0.f,0.f,0.f,0.f}; c2_[1] = (f32x4){0.f,0.f,0.f,0.f};           \
    _Pragma("unroll")                                                               \
    for (int ks = 0; ks < 8; ++ks) {                                                \
      bf16x8 hv = *(const bf16x8*)&(hb_)[ks * 32];                                  \
      bf16x8 wv0 = *(const bf16x8*)&wnb0[ks * 32];                                  \
      bf16x8 wv1 = *(const bf16x8*)&wnb1[ks * 32];                                  \
      c0_[0] = __builtin_amdgcn_mfma_f32_16x16x32_bf16(wfragR[0][ks], hv, c0_[0], 0, 0, 0); \
      c0_[1] = __builtin_amdgcn_mfma_f32_16x16x32_bf16(wfragR[1][ks], hv, c0_[1], 0, 0, 0); \
      c1_[0] = __builtin_amdgcn_mfma_f32_16x16x32_bf16(wfragZ[0][ks], hv, c1_[0], 0, 0, 0); \
      c1_[1] = __builtin_amdgcn_mfma_f32_16x16x32_bf16(wfragZ[1][ks], hv, c1_[1], 0, 0, 0); \
      c2_[0] = __builtin_amdgcn_mfma_f32_16x16x32_bf16(wv0, hv, c2_[0], 0, 0, 0);   \
      c2_[1] = __builtin_amdgcn_mfma_f32_16x16x32_bf16(wv1, hv, c2_[1], 0, 0, 0);   \
    }                                                                               \
  } while (0)

#define POINTWISE_GROUP(c0_, c1_, c2_, G_, hp_, len_, last_, b_, optr_, hf_)        \
  do {                                                                              \
    float hn_[2][4];                                                                \
    _Pragma("unroll")                                                               \
    for (int nt = 0; nt < 2; ++nt) {                                                \
      const unsigned short* g0 = (const unsigned short*)&G_[nt][0];                 \
      const unsigned short* g1 = (const unsigned short*)&G_[nt][1];                 \
      const unsigned short* g2 = (const unsigned short*)&G_[nt][2];                 \
      const unsigned short* hp16 = (const unsigned short*)&hp_[nt];                 \
      const float4 bnv = nt ? bn1 : bn0;                                            \
      _Pragma("unroll")                                                             \
      for (int qq = 0; qq < 4; ++qq) {                                              \
        float rr = sigm(bs2f(g0[qq]) + c0_[nt][qq]);                                \
        float zz = sigm(bs2f(g1[qq]) + c1_[nt][qq]);                                \
        float bnq = (qq == 0) ? bnv.x : (qq == 1) ? bnv.y : (qq == 2) ? bnv.z : bnv.w; \
        float nn = tanh_fast(bs2f(g2[qq]) + rr * (c2_[nt][qq] + bnq));              \
        hn_[nt][qq] = (1.f - zz) * nn + zz * bs2f(hp16[qq]);                        \
      }                                                                             \
    }                                                                               \
    if (i < len_) {                                                                 \
      float4 o0 = { hn_[0][0], hn_[0][1], hn_[0][2], hn_[0][3] };                   \
      float4 o1 = { hn_[1][0], hn_[1][1], hn_[1][2], hn_[1][3] };                   \
      *(float4*)&optr_[0] = o0;                                                     \
      *(float4*)&optr_[16] = o1;                                                    \
      if (last_ && i == len_ - 1) {                                                 \
        float* fp = out + (size_t)b_ * 256 + col0;                                  \
        *(float4*)&fp[0] = o0;                                                      \
        *(float4*)&fp[16] = o1;                                                     \
      }                                                                             \
    }                                                                               \
    if (i + 1 >= len_) {                                                            \
      _Pragma("unroll")                                                             \
      for (int nt = 0; nt < 2; ++nt)                                                \
        _Pragma("unroll")                                                           \
        for (int qq = 0; qq < 4; ++qq) hn_[nt][qq] = 0.f;                           \
    }                                                                               \
    hp_[0] = (short4v){ f2bs(hn_[0][0]), f2bs(hn_[0][1]), f2bs(hn_[0][2]), f2bs(hn_[0][3]) }; \
    hp_[1] = (short4v){ f2bs(hn_[1][0]), f2bs(hn_[1][1]), f2bs(hn_[1][2]), f2bs(hn_[1][3]) }; \
    *(short4v*)&hf_[l15 * HSTRIDE + col0] = hp_[0];                                 \
    *(short4v*)&hf_[l15 * HSTRIDE + col0 + 16] = hp_[1];                            \
  } while (0)

  // prologue: cA = MFMA_A(0)
  MFMA_GROUP(cA0, cA1, cA2, hbA);
  __syncthreads();

  for (int i = 0; i < nsteps; ++i) {
    // ---- phase alpha: MFMA_B(i) || pointwise_A(i) ----
    if (i > 0) { LOADG(GB, gptrB); if (i + 1 < lenB) gptrB += 64 * 768; }
    MFMA_GROUP(cB0, cB1, cB2, hbB);
    POINTWISE_GROUP(cA0, cA1, cA2, GA, hpA, lenA, lastA, bA, optrA, hfA);
    optrA += 64 * 256;
    __syncthreads();

    // ---- phase beta: MFMA_A(i+1) || pointwise_B(i); issue GA(i+1) ----
    LOADG(GA, gptrA); if (i + 2 < lenA) gptrA += 64 * 768;
    MFMA_GROUP(cA0, cA1, cA2, hbA);
    POINTWISE_GROUP(cB0, cB1, cB2, GB, hpB, lenB, lastB, bB, optrB, hfB);
    optrB += 64 * 256;
    __syncthreads();
  }
#undef MFMA_GROUP
#undef POINTWISE_GROUP
}

extern "C" void kernel_launch(void* const* d_in, const int* in_sizes, int n_in,
                              void* d_out, int out_size, void* d_ws, size_t ws_size,
                              hipStream_t stream) {
  const float* x   = (const float*)d_in[0];
  const void*  rin = d_in[1];
  const float* h0  = (const float*)d_in[2];
  const float* Wi  = (const float*)d_in[3];
  const float* bi  = (const float*)d_in[4];
  const float* Whr = (const float*)d_in[5];
  const float* Whz = (const float*)d_in[6];
  const float* Whn = (const float*)d_in[7];
  const float* bhn = (const float*)d_in[8];
  float* out = (float*)d_out;

  char* ws = (char*)d_ws;
  unsigned short* gi = (unsigned short*)(ws + WS_GI);
  uint8_t* rst       = (uint8_t*)(ws + WS_RST);
  int* flag          = (int*)(ws + WS_FLAG);
  uint64_t* desc     = (uint64_t*)(ws + WS_DESC);
  uint32_t* wgsteps  = (uint32_t*)(ws + WS_WGSTEPS);

  hipLaunchKernelGGL(detect_resets, dim3(1), dim3(256), 0, stream,
                     (const uint32_t*)rin, flag);
  hipLaunchKernelGGL(expand_resets, dim3(512), dim3(256), 0, stream, rin, flag, rst);
  hipLaunchKernelGGL(build_schedule, dim3(1), dim3(1024), 0, stream,
                     rst, desc, wgsteps);
  hipLaunchKernelGGL(gi_gemm_mfma, dim3(256), dim3(1024), 0, stream, x, Wi, bi, gi);
  hipLaunchKernelGGL(gru_rec_seg, dim3(NWG_REC), dim3(512), 0, stream,
                     gi, h0, Whr, Whz, Whn, bhn, desc, wgsteps, out);
}

// Round 12
// 2736.165 us; speedup vs baseline: 2.2936x; 2.2936x over previous
//
#include <hip/hip_runtime.h>
#include <hip/hip_bf16.h>
#include <cstdint>
#include <cstring>

#define T_DIM 2048
#define B_DIM 64
#define H_DIM 256
#define NSLOT 2048
#define NWG_REC 128
#define MAXLOC 1280
#define HSTRIDE 264   // shorts; 528B rows, 16B-aligned

typedef __attribute__((ext_vector_type(8))) short bf16x8;
typedef __attribute__((ext_vector_type(4))) float f32x4;
typedef __attribute__((ext_vector_type(4))) short short4v;

// ---------------- ws layout (bytes) ----------------
static const size_t WS_GI      = 0;           // 201326592  gi bf16 T*B*768 (direct (t,b) layout)
static const size_t WS_RST     = 201326592;   // 131072     resets u8
static const size_t WS_FLAG    = 201457664;   // 8          dtype flag
static const size_t WS_LIST    = 201457672;   // 1048576    seg list u64
static const size_t WS_ASSIGN  = 202506248;   // 524288     per-seg ofs u32
static const size_t WS_WGSTEPS = 203030536;   // 512        u32[128]
static const size_t WS_TL      = 203031048;   // 10485760   timeline u32[NSLOT][MAXLOC]
// end 213516808 (~213.5 MB, proven footprint)

// timeline record bits: t:0-10, b:11-16, ACTIVE:17, START:18, HINIT:19, FINAL:20
#define RB_ACT   (1u << 17)
#define RB_START (1u << 18)
#define RB_HINIT (1u << 19)
#define RB_FINAL (1u << 20)

static __device__ __forceinline__ short f2bs(float f) {
  __hip_bfloat16 b = __float2bfloat16(f);
  short s; memcpy(&s, &b, 2); return s;
}
static __device__ __forceinline__ float bs2f(unsigned short u) {
  uint32_t v = ((uint32_t)u) << 16; float f; memcpy(&f, &v, 4); return f;
}
static __device__ __forceinline__ float sigm(float x) {
  return 1.f / (1.f + __expf(-x));
}
static __device__ __forceinline__ float tanh_fast(float x) {
  return 1.f - 2.f / (__expf(2.f * x) + 1.f);
}

// ---------------- resets dtype detection (verified R1-R11) ----------------
__global__ __launch_bounds__(256) void detect_resets(const uint32_t* __restrict__ rbuf,
                                                     int* __restrict__ flag_out) {
  __shared__ int v_u8, v_f32;
  if (threadIdx.x == 0) { v_u8 = 0; v_f32 = 0; }
  __syncthreads();
  int cu = 0, cf = 0;
  for (int i = threadIdx.x; i < 32768; i += 256) {
    uint32_t w = rbuf[i];
    if (w == 0x3F800000u) cf++;
    else if (w > 1u && (w & 0xFEFEFEFEu) == 0u) cu++;
  }
  atomicAdd(&v_u8, cu);
  atomicAdd(&v_f32, cf);
  __syncthreads();
  if (threadIdx.x == 0) *flag_out = (v_f32 > 0) ? 2 : ((v_u8 > 0) ? 1 : 0);
}

__global__ __launch_bounds__(256) void expand_resets(const void* __restrict__ rbuf,
                                                     const int* __restrict__ flag,
                                                     uint8_t* __restrict__ out) {
  int i = blockIdx.x * 256 + threadIdx.x;
  if (i >= T_DIM * B_DIM) return;
  int f = *flag;
  uint8_t v;
  if (f == 1)      v = (((const uint8_t*)rbuf)[i] != 0);
  else if (f == 2) v = (((const float*)rbuf)[i] != 0.f);
  else             v = (((const int*)rbuf)[i] != 0);
  out[i] = v;
}

// ---------------- zero the timeline ----------------
__global__ __launch_bounds__(1024) void zero_tl(uint32_t* __restrict__ tl) {
  tl[(size_t)blockIdx.x * 1024 + threadIdx.x] = 0;
}

// ---------------- build segment schedule (parallel fill, verified R5-R8) ----------------
__global__ __launch_bounds__(1024) void build_schedule(const uint8_t* __restrict__ rst,
                                                       uint64_t* __restrict__ listG,
                                                       uint32_t* __restrict__ assignG,
                                                       uint32_t* __restrict__ wgsteps,
                                                       uint32_t* __restrict__ tl) {
  __shared__ uint32_t slotload[NSLOT];
  __shared__ uint32_t cnt[64];
  __shared__ uint32_t offs[65];
  __shared__ uint32_t nseg_s;
  const int tid = threadIdx.x;

  for (int i = tid; i < NSLOT; i += 1024) slotload[i] = 0;
  __syncthreads();

  if (tid < 64) {
    int b = tid, k = 1;
    for (int t = 1; t < 2048; ++t) k += rst[t * 64 + b];
    cnt[b] = k;
  }
  __syncthreads();
  if (tid == 0) {
    uint32_t a = 0;
    for (int b2 = 0; b2 < 64; ++b2) { offs[b2] = a; a += cnt[b2]; }
    offs[64] = a; nseg_s = a;
  }
  __syncthreads();
  // emit segments.  u64: b:0-7 | hinit:8 | start:16-27 | len:32-47
  if (tid < 64) {
    int b = tid;
    uint32_t o = offs[b];
    int h0flag = rst[b] ? 0 : 1;
    int prev = 0;
    for (int t = 1; t < 2048; ++t) {
      if (rst[t * 64 + b]) {
        uint32_t hin = (prev == 0) ? (uint32_t)h0flag : 0u;
        listG[o++] = ((uint64_t)(uint32_t)(t - prev) << 32) |
                     ((uint32_t)prev << 16) | (hin << 8) | (uint32_t)b;
        prev = t;
      }
    }
    uint32_t hin = (prev == 0) ? (uint32_t)h0flag : 0u;
    listG[o++] = ((uint64_t)(uint32_t)(2048 - prev) << 32) |
                 ((uint32_t)prev << 16) | (hin << 8) | (uint32_t)b;
  }
  __syncthreads();
  const uint32_t NSEG = nseg_s;

  for (uint32_t s = tid; s < NSEG; s += 1024) {
    uint32_t len = (uint32_t)(listG[s] >> 32) & 0xFFFFu;
    assignG[s] = atomicAdd(&slotload[s & (NSLOT - 1)], len);
  }
  __syncthreads();

  if (tid < NWG_REC) {
    uint32_t mx = 0;
#pragma unroll
    for (int q = 0; q < 16; ++q) {
      uint32_t v = slotload[q * NWG_REC + tid];
      mx = mx > v ? mx : v;
    }
    wgsteps[tid] = mx < MAXLOC ? mx : MAXLOC;
  }
  __syncthreads();

  // fill timeline: one wave per segment, lanes stride records
  const int wid = tid >> 6, ln = tid & 63;
  for (uint32_t s = wid; s < NSEG; s += 16) {
    uint64_t sg = listG[s];
    uint32_t slot = s & (NSLOT - 1);
    uint32_t ofs = assignG[s];
    uint32_t b = (uint32_t)sg & 63u;
    uint32_t hinit = ((uint32_t)sg >> 8) & 1u;
    uint32_t start = ((uint32_t)sg >> 16) & 0xFFFu;
    uint32_t len = (uint32_t)(sg >> 32) & 0xFFFFu;
    for (uint32_t i2 = ln; i2 < len; i2 += 64) {
      uint32_t rec = (start + i2) | (b << 11) | RB_ACT;
      if (i2 == 0) rec |= RB_START | (hinit << 19);
      if (i2 == len - 1 && start + len == 2048) rec |= RB_FINAL;
      if (ofs + i2 < MAXLOC) tl[(size_t)slot * MAXLOC + ofs + i2] = rec;
    }
  }
}

// ---------------- gi = x @ Wi + bi via MFMA (verified R2-R11) ----------------
__global__ __launch_bounds__(1024) void gi_gemm_mfma(const float* __restrict__ x,
                                                     const float* __restrict__ Wi,
                                                     const float* __restrict__ bi,
                                                     unsigned short* __restrict__ gi16) {
  __shared__ short hfrag[32 * 136];
  const int tid = threadIdx.x;
  const int lane = tid & 63, wave = tid >> 6;
  const int lq = lane >> 4, l15 = lane & 15;

  bf16x8 wfrag[3][8];
  const int colb = wave * 48 + l15;
#pragma unroll
  for (int nt = 0; nt < 3; ++nt) {
#pragma unroll
    for (int ks = 0; ks < 8; ++ks) {
      bf16x8 f;
#pragma unroll
      for (int e = 0; e < 8; ++e)
        f[e] = f2bs(Wi[(size_t)(ks * 32 + lq * 8 + e) * 768 + colb + nt * 16]);
      wfrag[nt][ks] = f;
    }
  }
  const float b0 = bi[colb], b1 = bi[colb + 16], b2 = bi[colb + 32];

  const int r = wave;
  const int kc = (tid & 63) * 4;
  const size_t m0 = (size_t)blockIdx.x * 32 * 16;

  float4 xv = *(const float4*)&x[(m0 + r) * 256 + kc];
  for (int i = 0; i < 32; ++i) {
    short4v xb = { f2bs(xv.x), f2bs(xv.y), f2bs(xv.z), f2bs(xv.w) };
    *(short4v*)&hfrag[(kc >> 3) * 136 + r * 8 + (kc & 7)] = xb;
    __syncthreads();
    if (i + 1 < 32)
      xv = *(const float4*)&x[(m0 + (size_t)(i + 1) * 16 + r) * 256 + kc];
    f32x4 c0 = {0.f,0.f,0.f,0.f}, c1 = {0.f,0.f,0.f,0.f}, c2 = {0.f,0.f,0.f,0.f};
#pragma unroll
    for (int ks = 0; ks < 8; ++ks) {
      bf16x8 a = *(const bf16x8*)&hfrag[(ks * 4 + lq) * 136 + l15 * 8];
      c0 = __builtin_amdgcn_mfma_f32_16x16x32_bf16(a, wfrag[0][ks], c0, 0, 0, 0);
      c1 = __builtin_amdgcn_mfma_f32_16x16x32_bf16(a, wfrag[1][ks], c1, 0, 0, 0);
      c2 = __builtin_amdgcn_mfma_f32_16x16x32_bf16(a, wfrag[2][ks], c2, 0, 0, 0);
    }
    __syncthreads();
    const size_t rowb = m0 + (size_t)i * 16;
#pragma unroll
    for (int qq = 0; qq < 4; ++qq) {
      const size_t row = rowb + lq * 4 + qq;
      gi16[row * 768 + colb]      = (unsigned short)f2bs(c0[qq] + b0);
      gi16[row * 768 + colb + 16] = (unsigned short)f2bs(c1[qq] + b1);
      gi16[row * 768 + colb + 32] = (unsigned short)f2bs(c2[qq] + b2);
    }
  }
}

// ---------------- segment-parallel GRU recurrence (R8 config, lgkm-only barrier) ----------------
// 128 WGs x 8 waves. Slot of MFMA-col l15 = l15*128 + wg. Wave w owns h-cols
// [w*32, w*32+32) as two 16-col tiles: Wr/Wz frags for BOTH tiles resident in
// registers (128, AGPR-placed, R8-proven no-spill), Wn^T staged in LDS.
// SINGLE CHANGE vs R8: the per-step barrier waits lgkmcnt(0) only (h-exchange
// through LDS), NOT vmcnt(0) — the 12 gi prefetch loads stay in flight across
// the barrier instead of being drained at L3 latency every step.
__global__ __launch_bounds__(512, 1) void gru_rec_seg(const unsigned short* __restrict__ gi16,
                                                      const float* __restrict__ h0,
                                                      const float* __restrict__ Whr,
                                                      const float* __restrict__ Whz,
                                                      const float* __restrict__ Whn,
                                                      const float* __restrict__ bhn,
                                                      const uint32_t* __restrict__ tl,
                                                      const uint32_t* __restrict__ wgsteps,
                                                      float* __restrict__ out) {
  __shared__ short wn_lds[256 * HSTRIDE];     // Wn^T: [col][k], 135KB
  __shared__ short hfrag[2][16 * HSTRIDE];    // h^T: [slot][hcol], 2x8.4KB
  const int tid = threadIdx.x;
  const int lane = tid & 63, w = tid >> 6;    // w in [0,8)
  const int lq = lane >> 4, l15 = lane & 15;
  const int wg = blockIdx.x;

  // resident Wr/Wz A-fragments for both tiles: rows = w*32 + nt*16 + l15
  bf16x8 wfragR[2][8], wfragZ[2][8];
#pragma unroll
  for (int nt = 0; nt < 2; ++nt) {
    const int wcol = w * 32 + nt * 16 + l15;
#pragma unroll
    for (int ks = 0; ks < 8; ++ks) {
      bf16x8 fr, fz;
#pragma unroll
      for (int e = 0; e < 8; ++e) {
        fr[e] = f2bs(Whr[(size_t)(ks * 32 + lq * 8 + e) * 256 + wcol]);
        fz[e] = f2bs(Whz[(size_t)(ks * 32 + lq * 8 + e) * 256 + wcol]);
      }
      wfragR[nt][ks] = fr; wfragZ[nt][ks] = fz;
    }
  }

  // stage Wn^T into LDS col-major: wn_lds[col*HSTRIDE + k]; 512 threads
  {
    const int col = tid & 255, kb = (tid >> 8) * 128;
    for (int kk = 0; kk < 128; kk += 4) {
      short4v v;
#pragma unroll
      for (int u = 0; u < 4; ++u)
        v[u] = f2bs(Whn[(size_t)(kb + kk + u) * 256 + col]);
      *(short4v*)&wn_lds[col * HSTRIDE + kb + kk] = v;
    }
  }

  const int colA = w * 32 + lq * 4;           // tile 0 cols; tile 1 = +16
  float4 bn0 = *(const float4*)&bhn[colA];
  float4 bn1 = *(const float4*)&bhn[colA + 16];
  const int nsteps = (int)wgsteps[wg];
  const uint32_t* tlb = tl + (size_t)(l15 * NWG_REC + wg) * MAXLOC;

  // pipelines: records depth-2, gi depth-1 (both tiles)
  uint32_t R0 = tlb[0], R1 = tlb[1];
  ushort4 G0[2][3];
  {
    size_t gb = ((size_t)(R0 & 0x7FFu) * 64 + ((R0 >> 11) & 63u)) * 768 + colA;
#pragma unroll
    for (int nt = 0; nt < 2; ++nt) {
      G0[nt][0] = *(const ushort4*)&gi16[gb + nt * 16];
      G0[nt][1] = *(const ushort4*)&gi16[gb + 256 + nt * 16];
      G0[nt][2] = *(const ushort4*)&gi16[gb + 512 + nt * 16];
    }
  }
  float hreg[2][4];
  {
    float4 hv0 = {0.f,0.f,0.f,0.f}, hv1 = {0.f,0.f,0.f,0.f};
    if ((R0 & RB_ACT) && (R0 & RB_START) && (R0 & RB_HINIT)) {
      size_t hb = (size_t)((R0 >> 11) & 63u) * 256 + colA;
      hv0 = *(const float4*)&h0[hb];
      hv1 = *(const float4*)&h0[hb + 16];
    }
    hreg[0][0]=hv0.x; hreg[0][1]=hv0.y; hreg[0][2]=hv0.z; hreg[0][3]=hv0.w;
    hreg[1][0]=hv1.x; hreg[1][1]=hv1.y; hreg[1][2]=hv1.z; hreg[1][3]=hv1.w;
    short4v b0v = { f2bs(hv0.x), f2bs(hv0.y), f2bs(hv0.z), f2bs(hv0.w) };
    short4v b1v = { f2bs(hv1.x), f2bs(hv1.y), f2bs(hv1.z), f2bs(hv1.w) };
    *(short4v*)&hfrag[0][l15 * HSTRIDE + colA] = b0v;
    *(short4v*)&hfrag[0][l15 * HSTRIDE + colA + 16] = b1v;
  }
  __syncthreads();

  int cur = 0;
  for (int i = 0; i < nsteps; ++i) {
    // prefetch record i+2 and gi for step i+1 (stay in flight across barrier)
    uint32_t R2 = (i + 2 < MAXLOC) ? tlb[i + 2] : 0u;
    ushort4 G1[2][3];
    {
      size_t gb = ((size_t)(R1 & 0x7FFu) * 64 + ((R1 >> 11) & 63u)) * 768 + colA;
#pragma unroll
      for (int nt = 0; nt < 2; ++nt) {
        G1[nt][0] = *(const ushort4*)&gi16[gb + nt * 16];
        G1[nt][1] = *(const ushort4*)&gi16[gb + 256 + nt * 16];
        G1[nt][2] = *(const ushort4*)&gi16[gb + 512 + nt * 16];
      }
    }

    // C[gate][tile] = W^T x h^T ; hv shared across gates & tiles
    f32x4 c0[2] = {{0.f,0.f,0.f,0.f},{0.f,0.f,0.f,0.f}};
    f32x4 c1[2] = {{0.f,0.f,0.f,0.f},{0.f,0.f,0.f,0.f}};
    f32x4 c2[2] = {{0.f,0.f,0.f,0.f},{0.f,0.f,0.f,0.f}};
    const short* hbase = &hfrag[cur][l15 * HSTRIDE + lq * 8];
    const short* wn0 = &wn_lds[(w * 32 + l15) * HSTRIDE + lq * 8];
    const short* wn1 = &wn_lds[(w * 32 + 16 + l15) * HSTRIDE + lq * 8];
#pragma unroll
    for (int ks = 0; ks < 8; ++ks) {
      bf16x8 hv = *(const bf16x8*)&hbase[ks * 32];
      bf16x8 wv0 = *(const bf16x8*)&wn0[ks * 32];
      bf16x8 wv1 = *(const bf16x8*)&wn1[ks * 32];
      c0[0] = __builtin_amdgcn_mfma_f32_16x16x32_bf16(wfragR[0][ks], hv, c0[0], 0, 0, 0);
      c0[1] = __builtin_amdgcn_mfma_f32_16x16x32_bf16(wfragR[1][ks], hv, c0[1], 0, 0, 0);
      c1[0] = __builtin_amdgcn_mfma_f32_16x16x32_bf16(wfragZ[0][ks], hv, c1[0], 0, 0, 0);
      c1[1] = __builtin_amdgcn_mfma_f32_16x16x32_bf16(wfragZ[1][ks], hv, c1[1], 0, 0, 0);
      c2[0] = __builtin_amdgcn_mfma_f32_16x16x32_bf16(wv0, hv, c2[0], 0, 0, 0);
      c2[1] = __builtin_amdgcn_mfma_f32_16x16x32_bf16(wv1, hv, c2[1], 0, 0, 0);
    }

    // pointwise: slot l15, cols colA..+3 (tile0) and colA+16..+19 (tile1)
    float hn[2][4];
#pragma unroll
    for (int nt = 0; nt < 2; ++nt) {
      const unsigned short* g0 = (const unsigned short*)&G0[nt][0];
      const unsigned short* g1 = (const unsigned short*)&G0[nt][1];
      const unsigned short* g2 = (const unsigned short*)&G0[nt][2];
      const float4 bnv = nt ? bn1 : bn0;
#pragma unroll
      for (int qq = 0; qq < 4; ++qq) {
        float rr = sigm(bs2f(g0[qq]) + c0[nt][qq]);
        float zz = sigm(bs2f(g1[qq]) + c1[nt][qq]);
        float bnq = (qq == 0) ? bnv.x : (qq == 1) ? bnv.y : (qq == 2) ? bnv.z : bnv.w;
        float nn = tanh_fast(bs2f(g2[qq]) + rr * (c2[nt][qq] + bnq));
        hn[nt][qq] = (1.f - zz) * nn + zz * hreg[nt][qq];
      }
    }
    if (R0 & RB_ACT) {
      uint32_t t = R0 & 0x7FFu, b = (R0 >> 11) & 63u;
      size_t ob = 16384 + ((size_t)t * 64 + b) * 256 + colA;
      float4 o0 = { hn[0][0], hn[0][1], hn[0][2], hn[0][3] };
      float4 o1 = { hn[1][0], hn[1][1], hn[1][2], hn[1][3] };
      *(float4*)&out[ob] = o0;
      *(float4*)&out[ob + 16] = o1;
      if (R0 & RB_FINAL) {
        size_t fb = (size_t)b * 256 + colA;
        *(float4*)&out[fb] = o0;
        *(float4*)&out[fb + 16] = o1;
      }
    }

    // next h per R1 flags
    if (!(R1 & RB_ACT)) {
#pragma unroll
      for (int nt = 0; nt < 2; ++nt)
#pragma unroll
        for (int qq = 0; qq < 4; ++qq) hn[nt][qq] = 0.f;
    } else if (R1 & RB_START) {
      if (R1 & RB_HINIT) {
        size_t hb2 = (size_t)((R1 >> 11) & 63u) * 256 + colA;
        float4 hv0 = *(const float4*)&h0[hb2];
        float4 hv1 = *(const float4*)&h0[hb2 + 16];
        hn[0][0]=hv0.x; hn[0][1]=hv0.y; hn[0][2]=hv0.z; hn[0][3]=hv0.w;
        hn[1][0]=hv1.x; hn[1][1]=hv1.y; hn[1][2]=hv1.z; hn[1][3]=hv1.w;
      } else {
#pragma unroll
        for (int nt = 0; nt < 2; ++nt)
#pragma unroll
          for (int qq = 0; qq < 4; ++qq) hn[nt][qq] = 0.f;
      }
    }
#pragma unroll
    for (int nt = 0; nt < 2; ++nt)
#pragma unroll
      for (int qq = 0; qq < 4; ++qq) hreg[nt][qq] = hn[nt][qq];

    short4v w0 = { f2bs(hn[0][0]), f2bs(hn[0][1]), f2bs(hn[0][2]), f2bs(hn[0][3]) };
    short4v w1 = { f2bs(hn[1][0]), f2bs(hn[1][1]), f2bs(hn[1][2]), f2bs(hn[1][3]) };
    *(short4v*)&hfrag[cur ^ 1][l15 * HSTRIDE + colA] = w0;
    *(short4v*)&hfrag[cur ^ 1][l15 * HSTRIDE + colA + 16] = w1;

    R0 = R1; R1 = R2;
#pragma unroll
    for (int nt = 0; nt < 2; ++nt) {
      G0[nt][0] = G1[nt][0]; G0[nt][1] = G1[nt][1]; G0[nt][2] = G1[nt][2];
    }
    cur ^= 1;

    // lgkm-only barrier: drain LDS (h-exchange) only; gi prefetch loads remain
    // in flight across the barrier (consumed next iter via compiler vmcnt).
    __builtin_amdgcn_sched_barrier(0);
    asm volatile("s_waitcnt lgkmcnt(0)" ::: "memory");
    __builtin_amdgcn_s_barrier();
    __builtin_amdgcn_sched_barrier(0);
  }
}

extern "C" void kernel_launch(void* const* d_in, const int* in_sizes, int n_in,
                              void* d_out, int out_size, void* d_ws, size_t ws_size,
                              hipStream_t stream) {
  const float* x   = (const float*)d_in[0];
  const void*  rin = d_in[1];
  const float* h0  = (const float*)d_in[2];
  const float* Wi  = (const float*)d_in[3];
  const float* bi  = (const float*)d_in[4];
  const float* Whr = (const float*)d_in[5];
  const float* Whz = (const float*)d_in[6];
  const float* Whn = (const float*)d_in[7];
  const float* bhn = (const float*)d_in[8];
  float* out = (float*)d_out;

  char* ws = (char*)d_ws;
  unsigned short* gi = (unsigned short*)(ws + WS_GI);
  uint8_t* rst       = (uint8_t*)(ws + WS_RST);
  int* flag          = (int*)(ws + WS_FLAG);
  uint64_t* listG    = (uint64_t*)(ws + WS_LIST);
  uint32_t* assignG  = (uint32_t*)(ws + WS_ASSIGN);
  uint32_t* wgsteps  = (uint32_t*)(ws + WS_WGSTEPS);
  uint32_t* tl       = (uint32_t*)(ws + WS_TL);

  hipLaunchKernelGGL(detect_resets, dim3(1), dim3(256), 0, stream,
                     (const uint32_t*)rin, flag);
  hipLaunchKernelGGL(expand_resets, dim3(512), dim3(256), 0, stream, rin, flag, rst);
  hipLaunchKernelGGL(zero_tl, dim3((NSLOT * MAXLOC) / 1024), dim3(1024), 0, stream, tl);
  hipLaunchKernelGGL(build_schedule, dim3(1), dim3(1024), 0, stream,
                     rst, listG, assignG, wgsteps, tl);
  hipLaunchKernelGGL(gi_gemm_mfma, dim3(256), dim3(1024), 0, stream, x, Wi, bi, gi);
  hipLaunchKernelGGL(gru_rec_seg, dim3(NWG_REC), dim3(512), 0, stream,
                     gi, h0, Whr, Whz, Whn, bhn, tl, wgsteps, out);
}

// Round 13
// 2390.390 us; speedup vs baseline: 2.6254x; 1.1447x over previous
//
#include <hip/hip_runtime.h>
#include <hip/hip_bf16.h>
#include <cstdint>
#include <cstring>

#define T_DIM 2048
#define B_DIM 64
#define H_DIM 256
#define NSLOT 2048
#define NWG_REC 128
#define MAXLOC 1280
#define HSTRIDE 264   // shorts; 528B rows, 16B-aligned

typedef __attribute__((ext_vector_type(8))) short bf16x8;
typedef __attribute__((ext_vector_type(4))) float f32x4;
typedef __attribute__((ext_vector_type(4))) short short4v;

// ---------------- ws layout (bytes) ----------------
static const size_t WS_GI      = 0;           // 201326592  gi bf16 T*B*768 (direct (t,b) layout)
static const size_t WS_RSTT    = 201326592;   // 131072     resets u8 TRANSPOSED [b][t]
static const size_t WS_FLAG    = 201457664;   // 8          dtype flag
static const size_t WS_LIST    = 201457672;   // 1048576    seg list u64
static const size_t WS_ASSIGN  = 202506248;   // 524288     per-seg ofs u32
static const size_t WS_WGSTEPS = 203030536;   // 512        u32[128]
static const size_t WS_TL      = 203031048;   // 10485760   timeline u32[NSLOT][MAXLOC]
// end 213516808 (~213.5 MB, proven footprint)

// timeline record bits: t:0-10, b:11-16, ACTIVE:17, START:18, HINIT:19, FINAL:20
#define RB_ACT   (1u << 17)
#define RB_START (1u << 18)
#define RB_HINIT (1u << 19)
#define RB_FINAL (1u << 20)

static __device__ __forceinline__ short f2bs(float f) {
  __hip_bfloat16 b = __float2bfloat16(f);
  short s; memcpy(&s, &b, 2); return s;
}
static __device__ __forceinline__ float bs2f(unsigned short u) {
  uint32_t v = ((uint32_t)u) << 16; float f; memcpy(&f, &v, 4); return f;
}
static __device__ __forceinline__ float sigm(float x) {
  return 1.f / (1.f + __expf(-x));
}
static __device__ __forceinline__ float tanh_fast(float x) {
  return 1.f - 2.f / (__expf(2.f * x) + 1.f);
}

// ---------------- resets dtype detection (verified R1-R12) ----------------
__global__ __launch_bounds__(256) void detect_resets(const uint32_t* __restrict__ rbuf,
                                                     int* __restrict__ flag_out) {
  __shared__ int v_u8, v_f32;
  if (threadIdx.x == 0) { v_u8 = 0; v_f32 = 0; }
  __syncthreads();
  int cu = 0, cf = 0;
  for (int i = threadIdx.x; i < 32768; i += 256) {
    uint32_t w = rbuf[i];
    if (w == 0x3F800000u) cf++;
    else if (w > 1u && (w & 0xFEFEFEFEu) == 0u) cu++;
  }
  atomicAdd(&v_u8, cu);
  atomicAdd(&v_f32, cf);
  __syncthreads();
  if (threadIdx.x == 0) *flag_out = (v_f32 > 0) ? 2 : ((v_u8 > 0) ? 1 : 0);
}

// expand + TRANSPOSE: rstT[b][t] contiguous per b -> build_schedule scans
// each row with u64 loads instead of 2048 strided byte loads (R12's hidden
// ~450us serial-latency cost).
__global__ __launch_bounds__(256) void expand_resets_T(const void* __restrict__ rbuf,
                                                       const int* __restrict__ flag,
                                                       uint8_t* __restrict__ outT) {
  int i = blockIdx.x * 256 + threadIdx.x;   // i = t*64 + b
  if (i >= T_DIM * B_DIM) return;
  int f = *flag;
  uint8_t v;
  if (f == 1)      v = (((const uint8_t*)rbuf)[i] != 0);
  else if (f == 2) v = (((const float*)rbuf)[i] != 0.f);
  else             v = (((const int*)rbuf)[i] != 0);
  int t = i >> 6, b = i & 63;
  outT[(size_t)b * 2048 + t] = v;
}

// ---------------- zero the timeline ----------------
__global__ __launch_bounds__(1024) void zero_tl(uint32_t* __restrict__ tl) {
  tl[(size_t)blockIdx.x * 1024 + threadIdx.x] = 0;
}

// ---------------- build segment schedule (word-scan, parallel fill) ----------------
// Per-b scans are 256 x u64 loads (contiguous, branchless count via popcll;
// emit via ffsll / m&=m-1 since bytes are 0/1). Replaces R12's 2048-iteration
// strided byte-load chains (~450us) with ~5us.
__global__ __launch_bounds__(1024) void build_schedule(const uint8_t* __restrict__ rstT,
                                                       uint64_t* __restrict__ listG,
                                                       uint32_t* __restrict__ assignG,
                                                       uint32_t* __restrict__ wgsteps,
                                                       uint32_t* __restrict__ tl) {
  __shared__ uint32_t slotload[NSLOT];
  __shared__ uint32_t cnt[64];
  __shared__ uint32_t offs[65];
  __shared__ uint32_t nseg_s;
  const int tid = threadIdx.x;

  for (int i = tid; i < NSLOT; i += 1024) slotload[i] = 0;
  __syncthreads();

  // count segments per b (branchless popcount over u64 words)
  if (tid < 64) {
    const uint64_t* row = (const uint64_t*)(rstT + (size_t)tid * 2048);
    uint32_t k = 1;
    for (int c = 0; c < 256; ++c) {
      uint64_t m = row[c];
      if (c == 0) m &= ~0xFFull;          // t=0 is not a boundary
      k += (uint32_t)__popcll(m);
    }
    cnt[tid] = k;
  }
  __syncthreads();
  if (tid == 0) {
    uint32_t a = 0;
    for (int b2 = 0; b2 < 64; ++b2) { offs[b2] = a; a += cnt[b2]; }
    offs[64] = a; nseg_s = a;
  }
  __syncthreads();
  // emit segments.  u64: b:0-7 | hinit:8 | start:16-27 | len:32-47
  if (tid < 64) {
    const int b = tid;
    const uint64_t* row = (const uint64_t*)(rstT + (size_t)b * 2048);
    uint32_t o = offs[b];
    const int h0flag = rstT[(size_t)b * 2048] ? 0 : 1;
    int prev = 0;
    for (int c = 0; c < 256; ++c) {
      uint64_t m = row[c];
      if (c == 0) m &= ~0xFFull;
      while (m) {
        int bit = __ffsll((unsigned long long)m) - 1;
        int t = c * 8 + (bit >> 3);
        uint32_t hin = (prev == 0) ? (uint32_t)h0flag : 0u;
        listG[o++] = ((uint64_t)(uint32_t)(t - prev) << 32) |
                     ((uint32_t)prev << 16) | (hin << 8) | (uint32_t)b;
        prev = t;
        m &= m - 1;                        // bytes are 0/1 -> one bit per byte
      }
    }
    uint32_t hin = (prev == 0) ? (uint32_t)h0flag : 0u;
    listG[o++] = ((uint64_t)(uint32_t)(2048 - prev) << 32) |
                 ((uint32_t)prev << 16) | (hin << 8) | (uint32_t)b;
  }
  __syncthreads();
  const uint32_t NSEG = nseg_s;

  for (uint32_t s = tid; s < NSEG; s += 1024) {
    uint32_t len = (uint32_t)(listG[s] >> 32) & 0xFFFFu;
    assignG[s] = atomicAdd(&slotload[s & (NSLOT - 1)], len);
  }
  __syncthreads();

  if (tid < NWG_REC) {
    uint32_t mx = 0;
#pragma unroll
    for (int q = 0; q < 16; ++q) {
      uint32_t v = slotload[q * NWG_REC + tid];
      mx = mx > v ? mx : v;
    }
    wgsteps[tid] = mx < MAXLOC ? mx : MAXLOC;
  }
  __syncthreads();

  // fill timeline: one wave per segment, lanes stride records
  const int wid = tid >> 6, ln = tid & 63;
  for (uint32_t s = wid; s < NSEG; s += 16) {
    uint64_t sg = listG[s];
    uint32_t slot = s & (NSLOT - 1);
    uint32_t ofs = assignG[s];
    uint32_t b = (uint32_t)sg & 63u;
    uint32_t hinit = ((uint32_t)sg >> 8) & 1u;
    uint32_t start = ((uint32_t)sg >> 16) & 0xFFFu;
    uint32_t len = (uint32_t)(sg >> 32) & 0xFFFFu;
    for (uint32_t i2 = ln; i2 < len; i2 += 64) {
      uint32_t rec = (start + i2) | (b << 11) | RB_ACT;
      if (i2 == 0) rec |= RB_START | (hinit << 19);
      if (i2 == len - 1 && start + len == 2048) rec |= RB_FINAL;
      if (ofs + i2 < MAXLOC) tl[(size_t)slot * MAXLOC + ofs + i2] = rec;
    }
  }
}

// ---------------- gi = x @ Wi + bi via MFMA (verified R2-R12) ----------------
__global__ __launch_bounds__(1024) void gi_gemm_mfma(const float* __restrict__ x,
                                                     const float* __restrict__ Wi,
                                                     const float* __restrict__ bi,
                                                     unsigned short* __restrict__ gi16) {
  __shared__ short hfrag[32 * 136];
  const int tid = threadIdx.x;
  const int lane = tid & 63, wave = tid >> 6;
  const int lq = lane >> 4, l15 = lane & 15;

  bf16x8 wfrag[3][8];
  const int colb = wave * 48 + l15;
#pragma unroll
  for (int nt = 0; nt < 3; ++nt) {
#pragma unroll
    for (int ks = 0; ks < 8; ++ks) {
      bf16x8 f;
#pragma unroll
      for (int e = 0; e < 8; ++e)
        f[e] = f2bs(Wi[(size_t)(ks * 32 + lq * 8 + e) * 768 + colb + nt * 16]);
      wfrag[nt][ks] = f;
    }
  }
  const float b0 = bi[colb], b1 = bi[colb + 16], b2 = bi[colb + 32];

  const int r = wave;
  const int kc = (tid & 63) * 4;
  const size_t m0 = (size_t)blockIdx.x * 32 * 16;

  float4 xv = *(const float4*)&x[(m0 + r) * 256 + kc];
  for (int i = 0; i < 32; ++i) {
    short4v xb = { f2bs(xv.x), f2bs(xv.y), f2bs(xv.z), f2bs(xv.w) };
    *(short4v*)&hfrag[(kc >> 3) * 136 + r * 8 + (kc & 7)] = xb;
    __syncthreads();
    if (i + 1 < 32)
      xv = *(const float4*)&x[(m0 + (size_t)(i + 1) * 16 + r) * 256 + kc];
    f32x4 c0 = {0.f,0.f,0.f,0.f}, c1 = {0.f,0.f,0.f,0.f}, c2 = {0.f,0.f,0.f,0.f};
#pragma unroll
    for (int ks = 0; ks < 8; ++ks) {
      bf16x8 a = *(const bf16x8*)&hfrag[(ks * 4 + lq) * 136 + l15 * 8];
      c0 = __builtin_amdgcn_mfma_f32_16x16x32_bf16(a, wfrag[0][ks], c0, 0, 0, 0);
      c1 = __builtin_amdgcn_mfma_f32_16x16x32_bf16(a, wfrag[1][ks], c1, 0, 0, 0);
      c2 = __builtin_amdgcn_mfma_f32_16x16x32_bf16(a, wfrag[2][ks], c2, 0, 0, 0);
    }
    __syncthreads();
    const size_t rowb = m0 + (size_t)i * 16;
#pragma unroll
    for (int qq = 0; qq < 4; ++qq) {
      const size_t row = rowb + lq * 4 + qq;
      gi16[row * 768 + colb]      = (unsigned short)f2bs(c0[qq] + b0);
      gi16[row * 768 + colb + 16] = (unsigned short)f2bs(c1[qq] + b1);
      gi16[row * 768 + colb + 32] = (unsigned short)f2bs(c2[qq] + b2);
    }
  }
}

// ---------------- segment-parallel GRU recurrence (R8 verbatim — best measured) ----------------
// 128 WGs x 8 waves. Slot of MFMA-col l15 = l15*128 + wg. Wave w owns h-cols
// [w*32, w*32+32) as two 16-col tiles: Wr/Wz frags for BOTH tiles resident in
// registers (128, AGPR-placed), Wn^T staged in LDS. __syncthreads per step.
__global__ __launch_bounds__(512, 1) void gru_rec_seg(const unsigned short* __restrict__ gi16,
                                                      const float* __restrict__ h0,
                                                      const float* __restrict__ Whr,
                                                      const float* __restrict__ Whz,
                                                      const float* __restrict__ Whn,
                                                      const float* __restrict__ bhn,
                                                      const uint32_t* __restrict__ tl,
                                                      const uint32_t* __restrict__ wgsteps,
                                                      float* __restrict__ out) {
  __shared__ short wn_lds[256 * HSTRIDE];     // Wn^T: [col][k], 135KB
  __shared__ short hfrag[2][16 * HSTRIDE];    // h^T: [slot][hcol], 2x8.4KB
  const int tid = threadIdx.x;
  const int lane = tid & 63, w = tid >> 6;    // w in [0,8)
  const int lq = lane >> 4, l15 = lane & 15;
  const int wg = blockIdx.x;

  bf16x8 wfragR[2][8], wfragZ[2][8];
#pragma unroll
  for (int nt = 0; nt < 2; ++nt) {
    const int wcol = w * 32 + nt * 16 + l15;
#pragma unroll
    for (int ks = 0; ks < 8; ++ks) {
      bf16x8 fr, fz;
#pragma unroll
      for (int e = 0; e < 8; ++e) {
        fr[e] = f2bs(Whr[(size_t)(ks * 32 + lq * 8 + e) * 256 + wcol]);
        fz[e] = f2bs(Whz[(size_t)(ks * 32 + lq * 8 + e) * 256 + wcol]);
      }
      wfragR[nt][ks] = fr; wfragZ[nt][ks] = fz;
    }
  }

  {
    const int col = tid & 255, kb = (tid >> 8) * 128;
    for (int kk = 0; kk < 128; kk += 4) {
      short4v v;
#pragma unroll
      for (int u = 0; u < 4; ++u)
        v[u] = f2bs(Whn[(size_t)(kb + kk + u) * 256 + col]);
      *(short4v*)&wn_lds[col * HSTRIDE + kb + kk] = v;
    }
  }

  const int colA = w * 32 + lq * 4;           // tile 0 cols; tile 1 = +16
  float4 bn0 = *(const float4*)&bhn[colA];
  float4 bn1 = *(const float4*)&bhn[colA + 16];
  const int nsteps = (int)wgsteps[wg];
  const uint32_t* tlb = tl + (size_t)(l15 * NWG_REC + wg) * MAXLOC;

  uint32_t R0 = tlb[0], R1 = tlb[1];
  ushort4 G0[2][3];
  {
    size_t gb = ((size_t)(R0 & 0x7FFu) * 64 + ((R0 >> 11) & 63u)) * 768 + colA;
#pragma unroll
    for (int nt = 0; nt < 2; ++nt) {
      G0[nt][0] = *(const ushort4*)&gi16[gb + nt * 16];
      G0[nt][1] = *(const ushort4*)&gi16[gb + 256 + nt * 16];
      G0[nt][2] = *(const ushort4*)&gi16[gb + 512 + nt * 16];
    }
  }
  float hreg[2][4];
  {
    float4 hv0 = {0.f,0.f,0.f,0.f}, hv1 = {0.f,0.f,0.f,0.f};
    if ((R0 & RB_ACT) && (R0 & RB_START) && (R0 & RB_HINIT)) {
      size_t hb = (size_t)((R0 >> 11) & 63u) * 256 + colA;
      hv0 = *(const float4*)&h0[hb];
      hv1 = *(const float4*)&h0[hb + 16];
    }
    hreg[0][0]=hv0.x; hreg[0][1]=hv0.y; hreg[0][2]=hv0.z; hreg[0][3]=hv0.w;
    hreg[1][0]=hv1.x; hreg[1][1]=hv1.y; hreg[1][2]=hv1.z; hreg[1][3]=hv1.w;
    short4v b0v = { f2bs(hv0.x), f2bs(hv0.y), f2bs(hv0.z), f2bs(hv0.w) };
    short4v b1v = { f2bs(hv1.x), f2bs(hv1.y), f2bs(hv1.z), f2bs(hv1.w) };
    *(short4v*)&hfrag[0][l15 * HSTRIDE + colA] = b0v;
    *(short4v*)&hfrag[0][l15 * HSTRIDE + colA + 16] = b1v;
  }
  __syncthreads();

  int cur = 0;
  for (int i = 0; i < nsteps; ++i) {
    uint32_t R2 = (i + 2 < MAXLOC) ? tlb[i + 2] : 0u;
    ushort4 G1[2][3];
    {
      size_t gb = ((size_t)(R1 & 0x7FFu) * 64 + ((R1 >> 11) & 63u)) * 768 + colA;
#pragma unroll
      for (int nt = 0; nt < 2; ++nt) {
        G1[nt][0] = *(const ushort4*)&gi16[gb + nt * 16];
        G1[nt][1] = *(const ushort4*)&gi16[gb + 256 + nt * 16];
        G1[nt][2] = *(const ushort4*)&gi16[gb + 512 + nt * 16];
      }
    }

    f32x4 c0[2] = {{0.f,0.f,0.f,0.f},{0.f,0.f,0.f,0.f}};
    f32x4 c1[2] = {{0.f,0.f,0.f,0.f},{0.f,0.f,0.f,0.f}};
    f32x4 c2[2] = {{0.f,0.f,0.f,0.f},{0.f,0.f,0.f,0.f}};
    const short* hbase = &hfrag[cur][l15 * HSTRIDE + lq * 8];
    const short* wn0 = &wn_lds[(w * 32 + l15) * HSTRIDE + lq * 8];
    const short* wn1 = &wn_lds[(w * 32 + 16 + l15) * HSTRIDE + lq * 8];
#pragma unroll
    for (int ks = 0; ks < 8; ++ks) {
      bf16x8 hv = *(const bf16x8*)&hbase[ks * 32];
      bf16x8 wv0 = *(const bf16x8*)&wn0[ks * 32];
      bf16x8 wv1 = *(const bf16x8*)&wn1[ks * 32];
      c0[0] = __builtin_amdgcn_mfma_f32_16x16x32_bf16(wfragR[0][ks], hv, c0[0], 0, 0, 0);
      c0[1] = __builtin_amdgcn_mfma_f32_16x16x32_bf16(wfragR[1][ks], hv, c0[1], 0, 0, 0);
      c1[0] = __builtin_amdgcn_mfma_f32_16x16x32_bf16(wfragZ[0][ks], hv, c1[0], 0, 0, 0);
      c1[1] = __builtin_amdgcn_mfma_f32_16x16x32_bf16(wfragZ[1][ks], hv, c1[1], 0, 0, 0);
      c2[0] = __builtin_amdgcn_mfma_f32_16x16x32_bf16(wv0, hv, c2[0], 0, 0, 0);
      c2[1] = __builtin_amdgcn_mfma_f32_16x16x32_bf16(wv1, hv, c2[1], 0, 0, 0);
    }

    float hn[2][4];
#pragma unroll
    for (int nt = 0; nt < 2; ++nt) {
      const unsigned short* g0 = (const unsigned short*)&G0[nt][0];
      const unsigned short* g1 = (const unsigned short*)&G0[nt][1];
      const unsigned short* g2 = (const unsigned short*)&G0[nt][2];
      const float4 bnv = nt ? bn1 : bn0;
#pragma unroll
      for (int qq = 0; qq < 4; ++qq) {
        float rr = sigm(bs2f(g0[qq]) + c0[nt][qq]);
        float zz = sigm(bs2f(g1[qq]) + c1[nt][qq]);
        float bnq = (qq == 0) ? bnv.x : (qq == 1) ? bnv.y : (qq == 2) ? bnv.z : bnv.w;
        float nn = tanh_fast(bs2f(g2[qq]) + rr * (c2[nt][qq] + bnq));
        hn[nt][qq] = (1.f - zz) * nn + zz * hreg[nt][qq];
      }
    }
    if (R0 & RB_ACT) {
      uint32_t t = R0 & 0x7FFu, b = (R0 >> 11) & 63u;
      size_t ob = 16384 + ((size_t)t * 64 + b) * 256 + colA;
      float4 o0 = { hn[0][0], hn[0][1], hn[0][2], hn[0][3] };
      float4 o1 = { hn[1][0], hn[1][1], hn[1][2], hn[1][3] };
      *(float4*)&out[ob] = o0;
      *(float4*)&out[ob + 16] = o1;
      if (R0 & RB_FINAL) {
        size_t fb = (size_t)b * 256 + colA;
        *(float4*)&out[fb] = o0;
        *(float4*)&out[fb + 16] = o1;
      }
    }

    if (!(R1 & RB_ACT)) {
#pragma unroll
      for (int nt = 0; nt < 2; ++nt)
#pragma unroll
        for (int qq = 0; qq < 4; ++qq) hn[nt][qq] = 0.f;
    } else if (R1 & RB_START) {
      if (R1 & RB_HINIT) {
        size_t hb2 = (size_t)((R1 >> 11) & 63u) * 256 + colA;
        float4 hv0 = *(const float4*)&h0[hb2];
        float4 hv1 = *(const float4*)&h0[hb2 + 16];
        hn[0][0]=hv0.x; hn[0][1]=hv0.y; hn[0][2]=hv0.z; hn[0][3]=hv0.w;
        hn[1][0]=hv1.x; hn[1][1]=hv1.y; hn[1][2]=hv1.z; hn[1][3]=hv1.w;
      } else {
#pragma unroll
        for (int nt = 0; nt < 2; ++nt)
#pragma unroll
          for (int qq = 0; qq < 4; ++qq) hn[nt][qq] = 0.f;
      }
    }
#pragma unroll
    for (int nt = 0; nt < 2; ++nt)
#pragma unroll
      for (int qq = 0; qq < 4; ++qq) hreg[nt][qq] = hn[nt][qq];

    short4v w0 = { f2bs(hn[0][0]), f2bs(hn[0][1]), f2bs(hn[0][2]), f2bs(hn[0][3]) };
    short4v w1 = { f2bs(hn[1][0]), f2bs(hn[1][1]), f2bs(hn[1][2]), f2bs(hn[1][3]) };
    *(short4v*)&hfrag[cur ^ 1][l15 * HSTRIDE + colA] = w0;
    *(short4v*)&hfrag[cur ^ 1][l15 * HSTRIDE + colA + 16] = w1;

    R0 = R1; R1 = R2;
#pragma unroll
    for (int nt = 0; nt < 2; ++nt) {
      G0[nt][0] = G1[nt][0]; G0[nt][1] = G1[nt][1]; G0[nt][2] = G1[nt][2];
    }
    cur ^= 1;
    __syncthreads();
  }
}

extern "C" void kernel_launch(void* const* d_in, const int* in_sizes, int n_in,
                              void* d_out, int out_size, void* d_ws, size_t ws_size,
                              hipStream_t stream) {
  const float* x   = (const float*)d_in[0];
  const void*  rin = d_in[1];
  const float* h0  = (const float*)d_in[2];
  const float* Wi  = (const float*)d_in[3];
  const float* bi  = (const float*)d_in[4];
  const float* Whr = (const float*)d_in[5];
  const float* Whz = (const float*)d_in[6];
  const float* Whn = (const float*)d_in[7];
  const float* bhn = (const float*)d_in[8];
  float* out = (float*)d_out;

  char* ws = (char*)d_ws;
  unsigned short* gi = (unsigned short*)(ws + WS_GI);
  uint8_t* rstT      = (uint8_t*)(ws + WS_RSTT);
  int* flag          = (int*)(ws + WS_FLAG);
  uint64_t* listG    = (uint64_t*)(ws + WS_LIST);
  uint32_t* assignG  = (uint32_t*)(ws + WS_ASSIGN);
  uint32_t* wgsteps  = (uint32_t*)(ws + WS_WGSTEPS);
  uint32_t* tl       = (uint32_t*)(ws + WS_TL);

  hipLaunchKernelGGL(detect_resets, dim3(1), dim3(256), 0, stream,
                     (const uint32_t*)rin, flag);
  hipLaunchKernelGGL(expand_resets_T, dim3(512), dim3(256), 0, stream, rin, flag, rstT);
  hipLaunchKernelGGL(zero_tl, dim3((NSLOT * MAXLOC) / 1024), dim3(1024), 0, stream, tl);
  hipLaunchKernelGGL(build_schedule, dim3(1), dim3(1024), 0, stream,
                     rstT, listG, assignG, wgsteps, tl);
  hipLaunchKernelGGL(gi_gemm_mfma, dim3(256), dim3(1024), 0, stream, x, Wi, bi, gi);
  hipLaunchKernelGGL(gru_rec_seg, dim3(NWG_REC), dim3(512), 0, stream,
                     gi, h0, Whr, Whz, Whn, bhn, tl, wgsteps, out);
}